// Round 1
// baseline (1978.256 us; speedup 1.0000x reference)
//
#include <hip/hip_runtime.h>

#define NN 200000
#define NE 2000000
#define NG 10000

__device__ __forceinline__ void fadd(float* p, float v) {
    // HW global_atomic_add_f32 (device-scope). Safe here: coarse-grained device mem.
    unsafeAtomicAdd(p, v);
}

// ---------------- node embedding: h = x @ node_w + node_b  [N,14]->[N,32]
__global__ __launch_bounds__(256) void k_node_embed(const float* __restrict__ x,
                                                    const float* __restrict__ w,
                                                    const float* __restrict__ b,
                                                    float* __restrict__ h) {
    __shared__ float sw[14 * 32];
    __shared__ float sb[32];
    for (int i = threadIdx.x; i < 14 * 32; i += 256) sw[i] = w[i];
    if (threadIdx.x < 32) sb[threadIdx.x] = b[threadIdx.x];
    __syncthreads();
    int n = blockIdx.x * 256 + threadIdx.x;
    if (n >= NN) return;
    float xi[14];
#pragma unroll
    for (int k = 0; k < 14; ++k) xi[k] = x[n * 14 + k];
#pragma unroll
    for (int c = 0; c < 32; c += 4) {
        float4 acc = make_float4(sb[c], sb[c + 1], sb[c + 2], sb[c + 3]);
#pragma unroll
        for (int k = 0; k < 14; ++k) {
            float xv = xi[k];
            acc.x += xv * sw[k * 32 + c + 0];
            acc.y += xv * sw[k * 32 + c + 1];
            acc.z += xv * sw[k * 32 + c + 2];
            acc.w += xv * sw[k * 32 + c + 3];
        }
        *(float4*)(h + n * 32 + c) = acc;
    }
}

// ---------------- fused edge phase: msg = relu(h[src] + edge_attr@ew + eb); agg[dst] += msg
// 8 threads per edge, 4 channels each.
__global__ __launch_bounds__(256) void k_edge_scatter(const int* __restrict__ ei,
                                                      const float* __restrict__ ea,
                                                      const float* __restrict__ ew,
                                                      const float* __restrict__ eb,
                                                      const float* __restrict__ h,
                                                      float* __restrict__ agg) {
    __shared__ float sw[96];
    __shared__ float sb[32];
    if (threadIdx.x < 96) sw[threadIdx.x] = ew[threadIdx.x];
    if (threadIdx.x < 32) sb[threadIdx.x] = eb[threadIdx.x];
    __syncthreads();
    int t = blockIdx.x * 256 + threadIdx.x;
    int edge = t >> 3;
    if (edge >= NE) return;
    int c = (t & 7) * 4;
    int src = ei[edge];
    int dst = ei[NE + edge];
    float a0 = ea[edge * 3 + 0];
    float a1 = ea[edge * 3 + 1];
    float a2 = ea[edge * 3 + 2];
    float4 hs = *(const float4*)(h + src * 32 + c);
    float m0 = hs.x + sb[c + 0] + a0 * sw[c + 0] + a1 * sw[32 + c + 0] + a2 * sw[64 + c + 0];
    float m1 = hs.y + sb[c + 1] + a0 * sw[c + 1] + a1 * sw[32 + c + 1] + a2 * sw[64 + c + 1];
    float m2 = hs.z + sb[c + 2] + a0 * sw[c + 2] + a1 * sw[32 + c + 2] + a2 * sw[64 + c + 2];
    float m3 = hs.w + sb[c + 3] + a0 * sw[c + 3] + a1 * sw[32 + c + 3] + a2 * sw[64 + c + 3];
    m0 = fmaxf(m0, 0.f);
    m1 = fmaxf(m1, 0.f);
    m2 = fmaxf(m2, 0.f);
    m3 = fmaxf(m3, 0.f);
    float* o = agg + (size_t)dst * 32 + c;
    fadd(o + 0, m0);
    fadd(o + 1, m1);
    fadd(o + 2, m2);
    fadd(o + 3, m3);
}

// ---------------- node MLP: z = relu((h+agg)@w1+b1)@w2+b2 ; writes z in-place over agg
__global__ __launch_bounds__(256) void k_mlp(const float* __restrict__ h,
                                             float* zio, // in: agg, out: z (same buffer)
                                             const float* __restrict__ w1,
                                             const float* __restrict__ b1,
                                             const float* __restrict__ w2,
                                             const float* __restrict__ b2) {
    __shared__ float sw1[75 * 32]; // transposed: [j][k]
    __shared__ float sw2[75 * 32]; // [j][k]
    __shared__ float sb1[75];
    __shared__ float sb2[32];
    for (int i = threadIdx.x; i < 2400; i += 256) {
        int k = i / 75, j = i % 75;
        sw1[j * 32 + k] = w1[i];
        sw2[i] = w2[i];
    }
    if (threadIdx.x < 75) sb1[threadIdx.x] = b1[threadIdx.x];
    if (threadIdx.x < 32) sb2[threadIdx.x] = b2[threadIdx.x];
    __syncthreads();
    int n = blockIdx.x * 256 + threadIdx.x;
    if (n >= NN) return;
    float z0[32], acc[32];
#pragma unroll
    for (int c = 0; c < 32; c += 4) {
        float4 hv = *(const float4*)(h + (size_t)n * 32 + c);
        float4 av = *(const float4*)(zio + (size_t)n * 32 + c);
        z0[c + 0] = hv.x + av.x;
        z0[c + 1] = hv.y + av.y;
        z0[c + 2] = hv.z + av.z;
        z0[c + 3] = hv.w + av.w;
    }
#pragma unroll
    for (int k = 0; k < 32; ++k) acc[k] = sb2[k];
    for (int j = 0; j < 75; ++j) {
        float tj = sb1[j];
#pragma unroll
        for (int k = 0; k < 32; ++k) tj += z0[k] * sw1[j * 32 + k];
        tj = fmaxf(tj, 0.f);
#pragma unroll
        for (int k = 0; k < 32; ++k) acc[k] += tj * sw2[j * 32 + k];
    }
#pragma unroll
    for (int c = 0; c < 32; c += 4) {
        *(float4*)(zio + (size_t)n * 32 + c) = make_float4(acc[c], acc[c + 1], acc[c + 2], acc[c + 3]);
    }
}

// ---------------- BN stats: stats[0..31]=sum, stats[32..63]=sumsq (per channel)
__global__ __launch_bounds__(256) void k_bn_stats(const float* __restrict__ z,
                                                  float* __restrict__ stats) {
    int tid = threadIdx.x;
    int gid = blockIdx.x * 256 + tid;
    float4 s = make_float4(0, 0, 0, 0), q = make_float4(0, 0, 0, 0);
    const int total = NN * 8; // float4 elements
    int stride = gridDim.x * 256;
    for (int i = gid; i < total; i += stride) {
        float4 v = *(const float4*)(z + (size_t)i * 4);
        s.x += v.x; s.y += v.y; s.z += v.z; s.w += v.w;
        q.x += v.x * v.x; q.y += v.y * v.y; q.z += v.z * v.z; q.w += v.w * v.w;
    }
    // reduce across lanes sharing (lane & 7): xor over bits 3..5
#pragma unroll
    for (int off = 8; off < 64; off <<= 1) {
        s.x += __shfl_xor(s.x, off); s.y += __shfl_xor(s.y, off);
        s.z += __shfl_xor(s.z, off); s.w += __shfl_xor(s.w, off);
        q.x += __shfl_xor(q.x, off); q.y += __shfl_xor(q.y, off);
        q.z += __shfl_xor(q.z, off); q.w += __shfl_xor(q.w, off);
    }
    __shared__ float ls[4][64];
    int wave = tid >> 6, lane = tid & 63;
    if (lane < 8) {
        int cb = lane * 4; // lane == tid&7 here
        ls[wave][cb + 0] = s.x; ls[wave][cb + 1] = s.y;
        ls[wave][cb + 2] = s.z; ls[wave][cb + 3] = s.w;
        ls[wave][32 + cb + 0] = q.x; ls[wave][32 + cb + 1] = q.y;
        ls[wave][32 + cb + 2] = q.z; ls[wave][32 + cb + 3] = q.w;
    }
    __syncthreads();
    if (tid < 64) {
        float v = ls[0][tid] + ls[1][tid] + ls[2][tid] + ls[3][tid];
        fadd(&stats[tid], v);
    }
}

// ---------------- BN finalize: deriv[0..31]=scale, deriv[32..63]=shift
__global__ void k_bn_finalize(const float* __restrict__ stats,
                              const float* __restrict__ g,
                              const float* __restrict__ b,
                              float* __restrict__ deriv) {
    int c = threadIdx.x;
    if (c >= 32) return;
    float mu = stats[c] * (1.0f / NN);
    float var = stats[32 + c] * (1.0f / NN) - mu * mu;
    float sc = g[c] * rsqrtf(var + 1e-5f);
    deriv[c] = sc;
    deriv[32 + c] = b[c] - mu * sc;
}

// ---------------- normalize + relu: h = relu(z*scale + shift)
__global__ __launch_bounds__(256) void k_norm_relu(const float* __restrict__ z,
                                                   const float* __restrict__ deriv,
                                                   float* __restrict__ h) {
    __shared__ float sc[32], sh[32];
    if (threadIdx.x < 32) {
        sc[threadIdx.x] = deriv[threadIdx.x];
        sh[threadIdx.x] = deriv[32 + threadIdx.x];
    }
    __syncthreads();
    int i = blockIdx.x * 256 + threadIdx.x;
    if (i >= NN * 8) return;
    int c = (i & 7) * 4;
    float4 v = *(const float4*)(z + (size_t)i * 4);
    float4 o;
    o.x = fmaxf(v.x * sc[c + 0] + sh[c + 0], 0.f);
    o.y = fmaxf(v.y * sc[c + 1] + sh[c + 1], 0.f);
    o.z = fmaxf(v.z * sc[c + 2] + sh[c + 2], 0.f);
    o.w = fmaxf(v.w * sc[c + 3] + sh[c + 3], 0.f);
    *(float4*)(h + (size_t)i * 4) = o;
}

// ---------------- pool: gsum[batch[n]] += h[n]; gcnt[batch[n]] += 1
__global__ __launch_bounds__(256) void k_pool(const float* __restrict__ h,
                                              const int* __restrict__ batch,
                                              float* __restrict__ gsum,
                                              float* __restrict__ gcnt) {
    int t = blockIdx.x * 256 + threadIdx.x;
    int node = t >> 3;
    if (node >= NN) return;
    int c = (t & 7) * 4;
    int b = batch[node];
    float4 v = *(const float4*)(h + (size_t)node * 32 + c);
    float* o = gsum + (size_t)b * 32 + c;
    fadd(o + 0, v.x);
    fadd(o + 1, v.y);
    fadd(o + 2, v.z);
    fadd(o + 3, v.w);
    if ((t & 7) == 0) fadd(&gcnt[b], 1.0f);
}

// ---------------- head: out = relu(gmean@l1+b1)@l2+b2
__global__ __launch_bounds__(256) void k_head(const float* __restrict__ gsum,
                                              const float* __restrict__ gcnt,
                                              const float* __restrict__ l1w,
                                              const float* __restrict__ l1b,
                                              const float* __restrict__ l2w,
                                              const float* __restrict__ l2b,
                                              float* __restrict__ out) {
    __shared__ float s1[32 * 16], sb1[16], s2[16 * 2], sb2[2];
    for (int i = threadIdx.x; i < 512; i += 256) s1[i] = l1w[i];
    if (threadIdx.x < 16) sb1[threadIdx.x] = l1b[threadIdx.x];
    if (threadIdx.x < 32) s2[threadIdx.x] = l2w[threadIdx.x];
    if (threadIdx.x < 2) sb2[threadIdx.x] = l2b[threadIdx.x];
    __syncthreads();
    int gi = blockIdx.x * 256 + threadIdx.x;
    if (gi >= NG) return;
    float inv = 1.0f / fmaxf(gcnt[gi], 1.0f);
    float gm[32];
#pragma unroll
    for (int c = 0; c < 32; c += 4) {
        float4 v = *(const float4*)(gsum + (size_t)gi * 32 + c);
        gm[c + 0] = v.x * inv;
        gm[c + 1] = v.y * inv;
        gm[c + 2] = v.z * inv;
        gm[c + 3] = v.w * inv;
    }
    float a[16];
#pragma unroll
    for (int j = 0; j < 16; ++j) {
        float t = sb1[j];
#pragma unroll
        for (int c = 0; c < 32; ++c) t += gm[c] * s1[c * 16 + j];
        a[j] = fmaxf(t, 0.f);
    }
    float o0 = sb2[0], o1 = sb2[1];
#pragma unroll
    for (int j = 0; j < 16; ++j) {
        o0 += a[j] * s2[j * 2 + 0];
        o1 += a[j] * s2[j * 2 + 1];
    }
    out[gi * 2 + 0] = o0;
    out[gi * 2 + 1] = o1;
}

extern "C" void kernel_launch(void* const* d_in, const int* in_sizes, int n_in,
                              void* d_out, int out_size, void* d_ws, size_t ws_size,
                              hipStream_t stream) {
    const float* x = (const float*)d_in[0];
    const int* ei = (const int*)d_in[1];
    const float* ea = (const float*)d_in[2];
    const int* batch = (const int*)d_in[3];
    const float* node_w = (const float*)d_in[4];
    const float* node_b = (const float*)d_in[5];
    const float* edge_w = (const float*)d_in[6];
    const float* edge_b = (const float*)d_in[7];
    const float* w1 = (const float*)d_in[8];
    const float* b1 = (const float*)d_in[9];
    const float* w2 = (const float*)d_in[10];
    const float* b2 = (const float*)d_in[11];
    const float* bng = (const float*)d_in[12];
    const float* bnb = (const float*)d_in[13];
    const float* l1w = (const float*)d_in[14];
    const float* l1b = (const float*)d_in[15];
    const float* l2w = (const float*)d_in[16];
    const float* l2b = (const float*)d_in[17];
    float* out = (float*)d_out;

    float* h = (float*)d_ws;                       // [NN*32]
    float* zb = h + (size_t)NN * 32;               // [NN*32] agg then z
    float* stats = zb + (size_t)NN * 32;           // [64] sums
    float* deriv = stats + 64;                     // [64] scale/shift
    float* gsum = stats + 128;                     // [NG*32]
    float* gcnt = gsum + (size_t)NG * 32;          // [NG]

    k_node_embed<<<(NN + 255) / 256, 256, 0, stream>>>(x, node_w, node_b, h);

    for (int l = 0; l < 2; ++l) {
        hipMemsetAsync(zb, 0, (size_t)NN * 32 * sizeof(float), stream);
        hipMemsetAsync(stats, 0, 64 * sizeof(float), stream);
        k_edge_scatter<<<(NE * 8) / 256, 256, 0, stream>>>(ei, ea, edge_w, edge_b, h, zb);
        k_mlp<<<(NN + 255) / 256, 256, 0, stream>>>(h, zb, w1 + l * 2400, b1 + l * 75,
                                                    w2 + l * 2400, b2 + l * 32);
        k_bn_stats<<<1024, 256, 0, stream>>>(zb, stats);
        k_bn_finalize<<<1, 64, 0, stream>>>(stats, bng + l * 32, bnb + l * 32, deriv);
        k_norm_relu<<<(NN * 8 + 255) / 256, 256, 0, stream>>>(zb, deriv, h);
    }

    hipMemsetAsync(gsum, 0, (size_t)(NG * 32 + NG) * sizeof(float), stream);
    k_pool<<<(NN * 8 + 255) / 256, 256, 0, stream>>>(h, batch, gsum, gcnt);
    k_head<<<(NG + 255) / 256, 256, 0, stream>>>(gsum, gcnt, l1w, l1b, l2w, l2b, out);
}

// Round 2
// 680.909 us; speedup vs baseline: 2.9053x; 2.9053x over previous
//
#include <hip/hip_runtime.h>

#define NN 200000
#define NE 2000000
#define NG 10000
#define NB_SCAN ((NN + 255) / 256)   // 782 blocks for node-count scans

__device__ __forceinline__ void fadd(float* p, float v) {
    unsafeAtomicAdd(p, v);  // HW global_atomic_add_f32
}

// ---------------- node embedding: h = x @ node_w + node_b  [N,14]->[N,32]
__global__ __launch_bounds__(256) void k_node_embed(const float* __restrict__ x,
                                                    const float* __restrict__ w,
                                                    const float* __restrict__ b,
                                                    float* __restrict__ h) {
    __shared__ float sw[14 * 32];
    __shared__ float sb[32];
    for (int i = threadIdx.x; i < 14 * 32; i += 256) sw[i] = w[i];
    if (threadIdx.x < 32) sb[threadIdx.x] = b[threadIdx.x];
    __syncthreads();
    int n = blockIdx.x * 256 + threadIdx.x;
    if (n >= NN) return;
    float xi[14];
#pragma unroll
    for (int k = 0; k < 14; ++k) xi[k] = x[n * 14 + k];
#pragma unroll
    for (int c = 0; c < 32; c += 4) {
        float4 acc = make_float4(sb[c], sb[c + 1], sb[c + 2], sb[c + 3]);
#pragma unroll
        for (int k = 0; k < 14; ++k) {
            float xv = xi[k];
            acc.x += xv * sw[k * 32 + c + 0];
            acc.y += xv * sw[k * 32 + c + 1];
            acc.z += xv * sw[k * 32 + c + 2];
            acc.w += xv * sw[k * 32 + c + 3];
        }
        *(float4*)(h + n * 32 + c) = acc;
    }
}

// ================= CSR build (once per launch) =================
__global__ __launch_bounds__(256) void k_deg_hist(const int* __restrict__ ei,
                                                  int* __restrict__ deg) {
    int e = blockIdx.x * 256 + threadIdx.x;
    if (e < NE) atomicAdd(&deg[ei[NE + e]], 1);
}

__global__ __launch_bounds__(256) void k_scan1(const int* __restrict__ deg,
                                               int* __restrict__ excl,
                                               int* __restrict__ part) {
    __shared__ int s[256];
    int tid = threadIdx.x;
    int i = blockIdx.x * 256 + tid;
    int v = (i < NN) ? deg[i] : 0;
    s[tid] = v;
    __syncthreads();
    for (int off = 1; off < 256; off <<= 1) {
        int t = (tid >= off) ? s[tid - off] : 0;
        __syncthreads();
        s[tid] += t;
        __syncthreads();
    }
    if (i < NN) excl[i] = s[tid] - v;
    if (tid == 255) part[blockIdx.x] = s[255];
}

__global__ __launch_bounds__(1024) void k_scan2(int* __restrict__ part) {
    __shared__ int s[1024];
    int tid = threadIdx.x;
    int v = (tid < NB_SCAN) ? part[tid] : 0;
    s[tid] = v;
    __syncthreads();
    for (int off = 1; off < 1024; off <<= 1) {
        int t = (tid >= off) ? s[tid - off] : 0;
        __syncthreads();
        s[tid] += t;
        __syncthreads();
    }
    if (tid < NB_SCAN) part[tid] = s[tid] - v;  // exclusive
}

__global__ __launch_bounds__(256) void k_scan3(int* __restrict__ row_off,
                                               const int* __restrict__ part,
                                               int* __restrict__ fill) {
    int i = blockIdx.x * 256 + threadIdx.x;
    if (i < NN) {
        int v = row_off[i] + part[blockIdx.x];
        row_off[i] = v;
        fill[i] = v;
    }
    if (i == 0) row_off[NN] = NE;
}

// scatter edges into dst-sorted order; also copy edge_attr into sorted layout
__global__ __launch_bounds__(256) void k_scatter_perm(const int* __restrict__ ei,
                                                      const float* __restrict__ ea,
                                                      int* __restrict__ fill,
                                                      int* __restrict__ src_s,
                                                      float* __restrict__ ea_s) {
    int e = blockIdx.x * 256 + threadIdx.x;
    if (e >= NE) return;
    int dst = ei[NE + e];
    int pos = atomicAdd(&fill[dst], 1);
    src_s[pos] = ei[e];
    ea_s[pos * 3 + 0] = ea[e * 3 + 0];
    ea_s[pos * 3 + 1] = ea[e * 3 + 1];
    ea_s[pos * 3 + 2] = ea[e * 3 + 2];
}

// ---------------- gather aggregation: agg[n] = sum_{e: dst=n} relu(h[src_e] + ea_e@ew + eb)
// 8 threads per node, 4 channels each. No atomics, single coalesced write.
__global__ __launch_bounds__(256) void k_aggregate(const int* __restrict__ row_off,
                                                   const int* __restrict__ src_s,
                                                   const float* __restrict__ ea_s,
                                                   const float* __restrict__ ew,
                                                   const float* __restrict__ eb,
                                                   const float* __restrict__ h,
                                                   float* __restrict__ agg) {
    __shared__ float sw[96];
    __shared__ float sb[32];
    if (threadIdx.x < 96) sw[threadIdx.x] = ew[threadIdx.x];
    if (threadIdx.x < 32) sb[threadIdx.x] = eb[threadIdx.x];
    __syncthreads();
    int t = blockIdx.x * 256 + threadIdx.x;
    int n = t >> 3;
    if (n >= NN) return;
    int c = (t & 7) * 4;
    float w0[4], w1[4], w2[4], bb[4];
#pragma unroll
    for (int j = 0; j < 4; ++j) {
        w0[j] = sw[c + j];
        w1[j] = sw[32 + c + j];
        w2[j] = sw[64 + c + j];
        bb[j] = sb[c + j];
    }
    float4 acc = make_float4(0.f, 0.f, 0.f, 0.f);
    int s0 = row_off[n], s1 = row_off[n + 1];
    for (int i = s0; i < s1; ++i) {
        int src = src_s[i];
        float a0 = ea_s[i * 3 + 0];
        float a1 = ea_s[i * 3 + 1];
        float a2 = ea_s[i * 3 + 2];
        float4 hs = *(const float4*)(h + (size_t)src * 32 + c);
        float m0 = hs.x + bb[0] + a0 * w0[0] + a1 * w1[0] + a2 * w2[0];
        float m1 = hs.y + bb[1] + a0 * w0[1] + a1 * w1[1] + a2 * w2[1];
        float m2 = hs.z + bb[2] + a0 * w0[2] + a1 * w1[2] + a2 * w2[2];
        float m3 = hs.w + bb[3] + a0 * w0[3] + a1 * w1[3] + a2 * w2[3];
        acc.x += fmaxf(m0, 0.f);
        acc.y += fmaxf(m1, 0.f);
        acc.z += fmaxf(m2, 0.f);
        acc.w += fmaxf(m3, 0.f);
    }
    *(float4*)(agg + (size_t)n * 32 + c) = acc;
}

// ---------------- fallback atomic scatter (used only if ws too small for CSR)
__global__ __launch_bounds__(256) void k_edge_scatter(const int* __restrict__ ei,
                                                      const float* __restrict__ ea,
                                                      const float* __restrict__ ew,
                                                      const float* __restrict__ eb,
                                                      const float* __restrict__ h,
                                                      float* __restrict__ agg) {
    __shared__ float sw[96];
    __shared__ float sb[32];
    if (threadIdx.x < 96) sw[threadIdx.x] = ew[threadIdx.x];
    if (threadIdx.x < 32) sb[threadIdx.x] = eb[threadIdx.x];
    __syncthreads();
    int t = blockIdx.x * 256 + threadIdx.x;
    int edge = t >> 3;
    if (edge >= NE) return;
    int c = (t & 7) * 4;
    int src = ei[edge];
    int dst = ei[NE + edge];
    float a0 = ea[edge * 3 + 0];
    float a1 = ea[edge * 3 + 1];
    float a2 = ea[edge * 3 + 2];
    float4 hs = *(const float4*)(h + src * 32 + c);
    float m0 = hs.x + sb[c + 0] + a0 * sw[c + 0] + a1 * sw[32 + c + 0] + a2 * sw[64 + c + 0];
    float m1 = hs.y + sb[c + 1] + a0 * sw[c + 1] + a1 * sw[32 + c + 1] + a2 * sw[64 + c + 1];
    float m2 = hs.z + sb[c + 2] + a0 * sw[c + 2] + a1 * sw[32 + c + 2] + a2 * sw[64 + c + 2];
    float m3 = hs.w + sb[c + 3] + a0 * sw[c + 3] + a1 * sw[32 + c + 3] + a2 * sw[64 + c + 3];
    float* o = agg + (size_t)dst * 32 + c;
    fadd(o + 0, fmaxf(m0, 0.f));
    fadd(o + 1, fmaxf(m1, 0.f));
    fadd(o + 2, fmaxf(m2, 0.f));
    fadd(o + 3, fmaxf(m3, 0.f));
}

// ---------------- node MLP: z = relu((h+agg)@w1+b1)@w2+b2 ; writes z in-place over agg
__global__ __launch_bounds__(256) void k_mlp(const float* __restrict__ h,
                                             float* zio,
                                             const float* __restrict__ w1,
                                             const float* __restrict__ b1,
                                             const float* __restrict__ w2,
                                             const float* __restrict__ b2) {
    __shared__ float sw1[75 * 32];  // transposed: [j][k]
    __shared__ float sw2[75 * 32];  // [j][k]
    __shared__ float sb1[75];
    __shared__ float sb2[32];
    for (int i = threadIdx.x; i < 2400; i += 256) {
        int k = i / 75, j = i % 75;
        sw1[j * 32 + k] = w1[i];
        sw2[i] = w2[i];
    }
    if (threadIdx.x < 75) sb1[threadIdx.x] = b1[threadIdx.x];
    if (threadIdx.x < 32) sb2[threadIdx.x] = b2[threadIdx.x];
    __syncthreads();
    int n = blockIdx.x * 256 + threadIdx.x;
    if (n >= NN) return;
    float z0[32], acc[32];
#pragma unroll
    for (int c = 0; c < 32; c += 4) {
        float4 hv = *(const float4*)(h + (size_t)n * 32 + c);
        float4 av = *(const float4*)(zio + (size_t)n * 32 + c);
        z0[c + 0] = hv.x + av.x;
        z0[c + 1] = hv.y + av.y;
        z0[c + 2] = hv.z + av.z;
        z0[c + 3] = hv.w + av.w;
    }
#pragma unroll
    for (int k = 0; k < 32; ++k) acc[k] = sb2[k];
    for (int j = 0; j < 75; ++j) {
        float tj = sb1[j];
#pragma unroll
        for (int k = 0; k < 32; ++k) tj += z0[k] * sw1[j * 32 + k];
        tj = fmaxf(tj, 0.f);
#pragma unroll
        for (int k = 0; k < 32; ++k) acc[k] += tj * sw2[j * 32 + k];
    }
#pragma unroll
    for (int c = 0; c < 32; c += 4) {
        *(float4*)(zio + (size_t)n * 32 + c) = make_float4(acc[c], acc[c + 1], acc[c + 2], acc[c + 3]);
    }
}

// ---------------- BN stats: stats[0..31]=sum, stats[32..63]=sumsq (per channel)
__global__ __launch_bounds__(256) void k_bn_stats(const float* __restrict__ z,
                                                  float* __restrict__ stats) {
    int tid = threadIdx.x;
    int gid = blockIdx.x * 256 + tid;
    float4 s = make_float4(0, 0, 0, 0), q = make_float4(0, 0, 0, 0);
    const int total = NN * 8;
    int stride = gridDim.x * 256;
    for (int i = gid; i < total; i += stride) {
        float4 v = *(const float4*)(z + (size_t)i * 4);
        s.x += v.x; s.y += v.y; s.z += v.z; s.w += v.w;
        q.x += v.x * v.x; q.y += v.y * v.y; q.z += v.z * v.z; q.w += v.w * v.w;
    }
#pragma unroll
    for (int off = 8; off < 64; off <<= 1) {
        s.x += __shfl_xor(s.x, off); s.y += __shfl_xor(s.y, off);
        s.z += __shfl_xor(s.z, off); s.w += __shfl_xor(s.w, off);
        q.x += __shfl_xor(q.x, off); q.y += __shfl_xor(q.y, off);
        q.z += __shfl_xor(q.z, off); q.w += __shfl_xor(q.w, off);
    }
    __shared__ float ls[4][64];
    int wave = tid >> 6, lane = tid & 63;
    if (lane < 8) {
        int cb = lane * 4;
        ls[wave][cb + 0] = s.x; ls[wave][cb + 1] = s.y;
        ls[wave][cb + 2] = s.z; ls[wave][cb + 3] = s.w;
        ls[wave][32 + cb + 0] = q.x; ls[wave][32 + cb + 1] = q.y;
        ls[wave][32 + cb + 2] = q.z; ls[wave][32 + cb + 3] = q.w;
    }
    __syncthreads();
    if (tid < 64) {
        float v = ls[0][tid] + ls[1][tid] + ls[2][tid] + ls[3][tid];
        fadd(&stats[tid], v);
    }
}

__global__ void k_bn_finalize(const float* __restrict__ stats,
                              const float* __restrict__ g,
                              const float* __restrict__ b,
                              float* __restrict__ deriv) {
    int c = threadIdx.x;
    if (c >= 32) return;
    float mu = stats[c] * (1.0f / NN);
    float var = stats[32 + c] * (1.0f / NN) - mu * mu;
    float sc = g[c] * rsqrtf(var + 1e-5f);
    deriv[c] = sc;
    deriv[32 + c] = b[c] - mu * sc;
}

__global__ __launch_bounds__(256) void k_norm_relu(const float* __restrict__ z,
                                                   const float* __restrict__ deriv,
                                                   float* __restrict__ h) {
    __shared__ float sc[32], sh[32];
    if (threadIdx.x < 32) {
        sc[threadIdx.x] = deriv[threadIdx.x];
        sh[threadIdx.x] = deriv[32 + threadIdx.x];
    }
    __syncthreads();
    int i = blockIdx.x * 256 + threadIdx.x;
    if (i >= NN * 8) return;
    int c = (i & 7) * 4;
    float4 v = *(const float4*)(z + (size_t)i * 4);
    float4 o;
    o.x = fmaxf(v.x * sc[c + 0] + sh[c + 0], 0.f);
    o.y = fmaxf(v.y * sc[c + 1] + sh[c + 1], 0.f);
    o.z = fmaxf(v.z * sc[c + 2] + sh[c + 2], 0.f);
    o.w = fmaxf(v.w * sc[c + 3] + sh[c + 3], 0.f);
    *(float4*)(h + (size_t)i * 4) = o;
}

__global__ __launch_bounds__(256) void k_pool(const float* __restrict__ h,
                                              const int* __restrict__ batch,
                                              float* __restrict__ gsum,
                                              float* __restrict__ gcnt) {
    int t = blockIdx.x * 256 + threadIdx.x;
    int node = t >> 3;
    if (node >= NN) return;
    int c = (t & 7) * 4;
    int b = batch[node];
    float4 v = *(const float4*)(h + (size_t)node * 32 + c);
    float* o = gsum + (size_t)b * 32 + c;
    fadd(o + 0, v.x);
    fadd(o + 1, v.y);
    fadd(o + 2, v.z);
    fadd(o + 3, v.w);
    if ((t & 7) == 0) fadd(&gcnt[b], 1.0f);
}

__global__ __launch_bounds__(256) void k_head(const float* __restrict__ gsum,
                                              const float* __restrict__ gcnt,
                                              const float* __restrict__ l1w,
                                              const float* __restrict__ l1b,
                                              const float* __restrict__ l2w,
                                              const float* __restrict__ l2b,
                                              float* __restrict__ out) {
    __shared__ float s1[32 * 16], sb1[16], s2[16 * 2], sb2[2];
    for (int i = threadIdx.x; i < 512; i += 256) s1[i] = l1w[i];
    if (threadIdx.x < 16) sb1[threadIdx.x] = l1b[threadIdx.x];
    if (threadIdx.x < 32) s2[threadIdx.x] = l2w[threadIdx.x];
    if (threadIdx.x < 2) sb2[threadIdx.x] = l2b[threadIdx.x];
    __syncthreads();
    int gi = blockIdx.x * 256 + threadIdx.x;
    if (gi >= NG) return;
    float inv = 1.0f / fmaxf(gcnt[gi], 1.0f);
    float gm[32];
#pragma unroll
    for (int c = 0; c < 32; c += 4) {
        float4 v = *(const float4*)(gsum + (size_t)gi * 32 + c);
        gm[c + 0] = v.x * inv;
        gm[c + 1] = v.y * inv;
        gm[c + 2] = v.z * inv;
        gm[c + 3] = v.w * inv;
    }
    float a[16];
#pragma unroll
    for (int j = 0; j < 16; ++j) {
        float t = sb1[j];
#pragma unroll
        for (int c = 0; c < 32; ++c) t += gm[c] * s1[c * 16 + j];
        a[j] = fmaxf(t, 0.f);
    }
    float o0 = sb2[0], o1 = sb2[1];
#pragma unroll
    for (int j = 0; j < 16; ++j) {
        o0 += a[j] * s2[j * 2 + 0];
        o1 += a[j] * s2[j * 2 + 1];
    }
    out[gi * 2 + 0] = o0;
    out[gi * 2 + 1] = o1;
}

extern "C" void kernel_launch(void* const* d_in, const int* in_sizes, int n_in,
                              void* d_out, int out_size, void* d_ws, size_t ws_size,
                              hipStream_t stream) {
    const float* x = (const float*)d_in[0];
    const int* ei = (const int*)d_in[1];
    const float* ea = (const float*)d_in[2];
    const int* batch = (const int*)d_in[3];
    const float* node_w = (const float*)d_in[4];
    const float* node_b = (const float*)d_in[5];
    const float* edge_w = (const float*)d_in[6];
    const float* edge_b = (const float*)d_in[7];
    const float* w1 = (const float*)d_in[8];
    const float* b1 = (const float*)d_in[9];
    const float* w2 = (const float*)d_in[10];
    const float* b2 = (const float*)d_in[11];
    const float* bng = (const float*)d_in[12];
    const float* bnb = (const float*)d_in[13];
    const float* l1w = (const float*)d_in[14];
    const float* l1b = (const float*)d_in[15];
    const float* l2w = (const float*)d_in[16];
    const float* l2b = (const float*)d_in[17];
    float* out = (float*)d_out;

    // workspace layout (units: float/4B)
    float* h = (float*)d_ws;                       // NN*32
    float* zb = h + (size_t)NN * 32;               // NN*32 (agg then z)
    float* stats = zb + (size_t)NN * 32;           // 64
    float* deriv = stats + 64;                     // 64
    float* gsum = stats + 128;                     // NG*32
    float* gcnt = gsum + (size_t)NG * 32;          // NG
    int* deg = (int*)(gcnt + NG);                  // NN
    int* row_off = deg + NN;                       // NN+1
    int* fill = row_off + NN + 1;                  // NN
    int* part = fill + NN;                         // 1024
    int* src_s = part + 1024;                      // NE
    float* ea_s = (float*)(src_s + NE);            // NE*3

    size_t need_f = (size_t)NN * 64 + 128 + (size_t)NG * 33 + (size_t)NN * 3 + 1 + 1024 + (size_t)NE * 4;
    bool use_csr = ws_size >= need_f * 4;

    k_node_embed<<<(NN + 255) / 256, 256, 0, stream>>>(x, node_w, node_b, h);

    if (use_csr) {
        hipMemsetAsync(deg, 0, (size_t)NN * sizeof(int), stream);
        k_deg_hist<<<(NE + 255) / 256, 256, 0, stream>>>(ei, deg);
        k_scan1<<<NB_SCAN, 256, 0, stream>>>(deg, row_off, part);
        k_scan2<<<1, 1024, 0, stream>>>(part);
        k_scan3<<<NB_SCAN, 256, 0, stream>>>(row_off, part, fill);
        k_scatter_perm<<<(NE + 255) / 256, 256, 0, stream>>>(ei, ea, fill, src_s, ea_s);
    }

    for (int l = 0; l < 2; ++l) {
        hipMemsetAsync(stats, 0, 64 * sizeof(float), stream);
        if (use_csr) {
            k_aggregate<<<(NN * 8 + 255) / 256, 256, 0, stream>>>(row_off, src_s, ea_s,
                                                                  edge_w, edge_b, h, zb);
        } else {
            hipMemsetAsync(zb, 0, (size_t)NN * 32 * sizeof(float), stream);
            k_edge_scatter<<<(NE * 8) / 256, 256, 0, stream>>>(ei, ea, edge_w, edge_b, h, zb);
        }
        k_mlp<<<(NN + 255) / 256, 256, 0, stream>>>(h, zb, w1 + l * 2400, b1 + l * 75,
                                                    w2 + l * 2400, b2 + l * 32);
        k_bn_stats<<<1024, 256, 0, stream>>>(zb, stats);
        k_bn_finalize<<<1, 64, 0, stream>>>(stats, bng + l * 32, bnb + l * 32, deriv);
        k_norm_relu<<<(NN * 8 + 255) / 256, 256, 0, stream>>>(zb, deriv, h);
    }

    hipMemsetAsync(gsum, 0, (size_t)(NG * 32 + NG) * sizeof(float), stream);
    k_pool<<<(NN * 8 + 255) / 256, 256, 0, stream>>>(h, batch, gsum, gcnt);
    k_head<<<(NG + 255) / 256, 256, 0, stream>>>(gsum, gcnt, l1w, l1b, l2w, l2b, out);
}